// Round 10
// baseline (1314.108 us; speedup 1.0000x reference)
//
#include <hip/hip_runtime.h>
#include <hip/hip_bf16.h>
#include <stdint.h>

#define NBIG 2176
#define OUTD 384

typedef __attribute__((ext_vector_type(8))) short s16x8;
typedef __attribute__((ext_vector_type(4))) float f32x4;
typedef __attribute__((ext_vector_type(4))) uint32_t u32x4;

// workspace layout (bytes)
#define WS_WGT   0u                    // bf16 [512][64]   g-weights transposed [N][K]
#define WS_WFC   (64u*1024u)           // bf16 [256][320]  fc1 augmented, transposed
#define WS_WBIG  (224u*1024u)          // bf16 [2304][320] big augmented, transposed (padded rows zero)
#define WS_C1    (1664u*1024u)         // f32 [256]
#define WS_C2    (1665u*1024u)         // f32 [2304]
#define WS_ACT   (2u*1024u*1024u)      // bf16 [65536][320]  u_aug

__device__ __forceinline__ float bs2f(short s) {
    uint32_t u = ((uint32_t)(uint16_t)s) << 16; float f; __builtin_memcpy(&f, &u, 4); return f;
}
__device__ __forceinline__ short f2bs(float f) {
    __hip_bfloat16 h = __float2bfloat16(f); short s; __builtin_memcpy(&s, &h, 2); return s;
}
__device__ __forceinline__ uint32_t swz(uint32_t row, uint32_t kb) { return kb ^ ((row & 7u) << 4); }

__device__ __forceinline__ f32x4 mfma16(s16x8 a, s16x8 b, f32x4 c) {
    asm volatile("v_mfma_f32_16x16x32_bf16 %0, %1, %2, %0" : "+v"(c) : "v"(a), "v"(b));
    return c;
}

// ---------------- weight prep (unchanged from r2, all passing) ----------------
__global__ __launch_bounds__(256) void k0a(const float* __restrict__ f1w, const float* __restrict__ f2w, char* ws) {
    int idx = blockIdx.x * 256 + threadIdx.x;   // 32768
    int n = idx >> 6, k = idx & 63;
    float v = (n < 256) ? f1w[k * 512 + n] : f2w[k * 512 + (n - 256)];
    ((short*)(ws + WS_WGT))[n * 64 + k] = f2bs(v);
}

__global__ __launch_bounds__(256) void k0b(const float* __restrict__ f1w, const float* __restrict__ f1b,
                                           const float* __restrict__ fc1, char* ws) {
    __shared__ float awt[256][65];
    __shared__ float fcc[256][16];
    const int tid = threadIdx.x;
    const int n0 = blockIdx.x * 16;
#pragma unroll 4
    for (int i = 0; i < 64; ++i) awt[tid][i] = f1w[i * 512 + 256 + tid];
#pragma unroll 4
    for (int i = 0; i < 16; ++i) {
        int idx = tid + i * 256; int j = idx >> 4, nl = idx & 15;
        fcc[j][nl] = fc1[j * 256 + n0 + nl];
    }
    __syncthreads();
    const int nl = tid & 15, rg = tid >> 4;
    float a0 = 0.f, a1v = 0.f, a2v = 0.f, a3v = 0.f;
    for (int j = 0; j < 256; ++j) {
        float wv = fcc[j][nl];
        a0 += awt[j][rg * 4 + 0] * wv; a1v += awt[j][rg * 4 + 1] * wv;
        a2v += awt[j][rg * 4 + 2] * wv; a3v += awt[j][rg * 4 + 3] * wv;
    }
    short* wfcT = (short*)(ws + WS_WFC);
    const int n = n0 + nl;
    wfcT[n * 320 + 256 + rg * 4 + 0] = f2bs(a0);
    wfcT[n * 320 + 256 + rg * 4 + 1] = f2bs(a1v);
    wfcT[n * 320 + 256 + rg * 4 + 2] = f2bs(a2v);
    wfcT[n * 320 + 256 + rg * 4 + 3] = f2bs(a3v);
#pragma unroll
    for (int p = 0; p < 16; ++p) { int k = rg * 16 + p; wfcT[n * 320 + k] = f2bs(fcc[k][nl]); }
    if (rg == 0) {
        float s = 0.f;
        for (int j = 0; j < 256; ++j) s += f1b[256 + j] * fcc[j][nl];
        ((float*)(ws + WS_C1))[n] = s;
    }
}

__global__ __launch_bounds__(256) void k0c(const float* __restrict__ f2w, const float* __restrict__ f2b,
                                           const float* __restrict__ invw, const float* __restrict__ wemb, char* ws) {
    __shared__ float awt[256][65];
    __shared__ float wbc[256][16];
    const int tid = threadIdx.x;
    short* wbT = (short*)(ws + WS_WBIG);
    if (blockIdx.x == 136) {
        for (int i = 0; i < 160; ++i) wbT[2176 * 320 + tid + i * 256] = 0;
        if (tid < 128) ((float*)(ws + WS_C2))[2176 + tid] = 0.f;
        return;
    }
    const int n0 = blockIdx.x * 16;
#pragma unroll 4
    for (int i = 0; i < 64; ++i) awt[tid][i] = f2w[i * 512 + 256 + tid];
#pragma unroll 4
    for (int i = 0; i < 16; ++i) {
        int idx = tid + i * 256; int j = idx >> 4, nl = idx & 15; int n = n0 + nl;
        wbc[j][nl] = (n < 128) ? invw[j * 128 + n] : wemb[j * 2048 + (n - 128)];
    }
    __syncthreads();
    const int nl = tid & 15, rg = tid >> 4;
    float a0 = 0.f, a1v = 0.f, a2v = 0.f, a3v = 0.f;
    for (int j = 0; j < 256; ++j) {
        float wv = wbc[j][nl];
        a0 += awt[j][rg * 4 + 0] * wv; a1v += awt[j][rg * 4 + 1] * wv;
        a2v += awt[j][rg * 4 + 2] * wv; a3v += awt[j][rg * 4 + 3] * wv;
    }
    const int n = n0 + nl;
    wbT[n * 320 + 256 + rg * 4 + 0] = f2bs(a0);
    wbT[n * 320 + 256 + rg * 4 + 1] = f2bs(a1v);
    wbT[n * 320 + 256 + rg * 4 + 2] = f2bs(a2v);
    wbT[n * 320 + 256 + rg * 4 + 3] = f2bs(a3v);
#pragma unroll
    for (int p = 0; p < 16; ++p) { int k = rg * 16 + p; wbT[n * 320 + k] = f2bs(wbc[k][nl]); }
    if (rg == 0) {
        float s = 0.f;
        for (int j = 0; j < 256; ++j) s += f2b[256 + j] * wbc[j][nl];
        ((float*)(ws + WS_C2))[n] = s;
    }
}

// ---------------- af: fused FiLM1 + fc1 + FiLM2 -> u_aug; operands in regs, only sT/sG2 in LDS ----------------
__global__ __launch_bounds__(512, 2) void af(const float* __restrict__ feat, const float* __restrict__ cond,
                                             const float* __restrict__ f1b, const float* __restrict__ f2b, char* ws) {
    __shared__ char sm[65536];          // sT [0,32K): 64x256 bf16 stride 512, swizzled; sG2 [32K,64K)
    char* sT = sm; char* sG2 = sm + 32768;
    const int tid = threadIdx.x;
    const int r0 = blockIdx.x * 64;
    short* actw = (short*)(ws + WS_ACT);
    const char* wfc = ws + WS_WFC;
    const char* wgt = ws + WS_WGT;
    const int w = tid >> 6, l = tid & 63, lr = l & 15, lk = l >> 4;
    const int wm = w >> 2, wn = w & 3;

    // phase-2 B prefetch (Wfc), direct to fragment regs, 2-deep
    s16x8 F0[8], F1[8];
#define AF_ISSUE(BUF, KC) do { \
    const char* bp_ = wfc + (size_t)(wn * 64 + lr) * 640 + ((KC) * 64 + lk * 8) * 2; \
    _Pragma("unroll") for (int fn_ = 0; fn_ < 4; ++fn_) \
    _Pragma("unroll") for (int ks_ = 0; ks_ < 2; ++ks_) \
        BUF[fn_ * 2 + ks_] = *(const s16x8*)(bp_ + fn_ * (16 * 640) + ks_ * 64); } while (0)

    // cond fragments (f32 -> bf16), rows fm*16+lr, k = ks*32+lk*8
    s16x8 caf[4][2];
#pragma unroll
    for (int fm = 0; fm < 4; ++fm)
#pragma unroll
        for (int ks = 0; ks < 2; ++ks) {
            const float* cp = cond + (size_t)(r0 + fm * 16 + lr) * 64 + ks * 32 + lk * 8;
            f32x4 c0 = *(const f32x4*)cp, c1 = *(const f32x4*)(cp + 4);
            s16x8 p;
#pragma unroll
            for (int j = 0; j < 4; ++j) { p[j] = f2bs(c0[j]); p[4 + j] = f2bs(c1[j]); }
            caf[fm][ks] = p;
        }
    {   // cond dual-store into act cols 256..319 (coalesced)
        int row = tid >> 3, g = tid & 7;
        const float* src = cond + (size_t)(r0 + row) * 64 + g * 8;
        s16x8 p;
#pragma unroll
        for (int j = 0; j < 8; ++j) p[j] = f2bs(src[j]);
        *(s16x8*)(actw + (size_t)(r0 + row) * 320 + 256 + g * 8) = p;
    }
    // phase-1 B fragments (WgT) direct from global
    s16x8 wgf[4][2];
#pragma unroll
    for (int fn = 0; fn < 4; ++fn)
#pragma unroll
        for (int ks = 0; ks < 2; ++ks)
            wgf[fn][ks] = *(const s16x8*)(wgt + (size_t)(w * 64 + fn * 16 + lr) * 128 + (ks * 32 + lk * 8) * 2);

    // phase 1: g = cond @ WgT  (8 waves x 64 cols)
    const int nw = w * 64;
    f32x4 acc[4][4] = {};
#pragma unroll
    for (int ks = 0; ks < 2; ++ks)
#pragma unroll
        for (int fm = 0; fm < 4; ++fm)
#pragma unroll
            for (int fn = 0; fn < 4; ++fn)
                acc[fm][fn] = mfma16(caf[fm][ks], wgf[fn][ks], acc[fm][fn]);
    asm volatile("s_nop 7\n\ts_nop 7");

    AF_ISSUE(F0, 0);                    // fire Wfc chunks now; latency hides under epilogue
    AF_ISSUE(F1, 1);

    if (nw < 256) {     // g1 -> t = feat*g1 -> sT
#pragma unroll
        for (int fm = 0; fm < 4; ++fm)
#pragma unroll
            for (int fn = 0; fn < 4; ++fn) {
                int c = nw + fn * 16 + lr;
                float bias = f1b[c];
#pragma unroll
                for (int ri = 0; ri < 4; ++ri) {
                    int row = fm * 16 + lk * 4 + ri;
                    float g1 = acc[fm][fn][ri] + bias;
                    float t = feat[(size_t)(r0 + row) * 512 + c] * g1;
                    *(short*)(sT + row * 512 + (((uint32_t)(c * 2)) ^ ((row & 7u) << 4))) = f2bs(t);
                }
            }
    } else {            // g2 -> sG2
#pragma unroll
        for (int fm = 0; fm < 4; ++fm)
#pragma unroll
            for (int fn = 0; fn < 4; ++fn) {
                int cg = nw - 256 + fn * 16 + lr;
                float bias = f2b[cg];
#pragma unroll
                for (int ri = 0; ri < 4; ++ri) {
                    int row = fm * 16 + lk * 4 + ri;
                    *(short*)(sG2 + row * 512 + (((uint32_t)(cg * 2)) ^ ((row & 7u) << 4))) = f2bs(acc[fm][fn][ri] + bias);
                }
            }
    }
    __syncthreads();    // sT/sG2 ready; the only barrier in af

    // phase 2: s = [t|cond] @ WfcT_aug, K=320 as 5 chunks, barrier-free
    f32x4 acc2[2][4] = {};
#define AF_CHUNK(BUF, KC) do { \
    _Pragma("unroll") for (int ks = 0; ks < 2; ++ks) { \
        uint32_t kb_ = (ks * 32 + lk * 8) * 2; \
        s16x8 a2f[2]; \
        _Pragma("unroll") for (int fm = 0; fm < 2; ++fm) { \
            int row = wm * 32 + fm * 16 + lr; \
            if ((KC) < 4) a2f[fm] = *(const s16x8*)(sT + row * 512 + swz(row, (KC) * 128 + kb_)); \
            else          a2f[fm] = caf[wm * 2 + fm][ks]; } \
        _Pragma("unroll") for (int fm = 0; fm < 2; ++fm) \
        _Pragma("unroll") for (int fn = 0; fn < 4; ++fn) \
            acc2[fm][fn] = mfma16(a2f[fm], BUF[fn * 2 + ks], acc2[fm][fn]); } \
    if ((KC) + 2 <= 4) AF_ISSUE(BUF, (KC) + 2); } while (0)

    AF_CHUNK(F0, 0); AF_CHUNK(F1, 1); AF_CHUNK(F0, 2); AF_CHUNK(F1, 3); AF_CHUNK(F0, 4);

    asm volatile("s_nop 7\n\ts_nop 7");
    const float* c1 = (const float*)(ws + WS_C1);
#pragma unroll
    for (int fm = 0; fm < 2; ++fm)
#pragma unroll
        for (int fn = 0; fn < 4; ++fn) {
            int c = wn * 64 + fn * 16 + lr;
            float cc1 = c1[c];
#pragma unroll
            for (int ri = 0; ri < 4; ++ri) {
                int row = wm * 32 + fm * 16 + lk * 4 + ri;
                float s = acc2[fm][fn][ri] + cc1;
                float g2v = bs2f(*(const short*)(sG2 + row * 512 + (((uint32_t)(c * 2)) ^ ((row & 7u) << 4))));
                actw[(size_t)(r0 + row) * 320 + c] = f2bs(s * g2v);
            }
        }
#undef AF_CHUNK
#undef AF_ISSUE
}

// ---------------- kb: out_all = u_aug @ WbigT_aug + fused einsum; A in regs, B direct-global, no main-loop barriers ----------------
__global__ __launch_bounds__(512, 2) void kb(const float* __restrict__ feat, char* ws, float* __restrict__ out) {
    __shared__ char sm[98304];          // sW [0,32K): 64x256 bf16 stride 512; sX [32K,96K): 64x256 f32 stride 1024, swizzled
    char* sWm = sm; char* sXm = sm + 32768;
    const int tid = threadIdx.x;
    const int r0 = blockIdx.x * 64;
    const char* actb = ws + WS_ACT;
    const char* wbig = ws + WS_WBIG;
    const float* c2 = (const float*)(ws + WS_C2);
    const int w = tid >> 6, l = tid & 63, lr = l & 15, lk = l >> 4;
    const int wm = w >> 2, wn = w & 3;  // wave tile: rows wm*32..+32, cols wn*64..+64 within N-tile of 256

    // B fragment pipeline, direct global -> regs, 2-deep, q = nt*5+kc in [0,45)
    s16x8 B0[8], B1[8];
    int ntI = 0, kcI = 0, qNext = 0;
    auto issue = [&](s16x8 (&B)[8]) {
        if (qNext <= 44) {
            const char* bp = wbig + (size_t)(ntI * 256 + wn * 64 + lr) * 640 + (kcI * 64 + lk * 8) * 2;
#pragma unroll
            for (int fn = 0; fn < 4; ++fn)
#pragma unroll
                for (int ks = 0; ks < 2; ++ks)
                    B[fn * 2 + ks] = *(const s16x8*)(bp + fn * (16 * 640) + ks * 64);
            ++qNext; if (++kcI == 5) { kcI = 0; ++ntI; }
        }
    };
    issue(B0); issue(B1);

    {   // stage feat equiv region -> sX (f32, coalesced loads, XOR-swizzled stores)
        int row = tid >> 3, seg = tid & 7;
        const float* src = feat + (size_t)(r0 + row) * 512 + 256 + seg * 32;
#pragma unroll
        for (int q = 0; q < 8; ++q) {
            f32x4 v = *(const f32x4*)(src + q * 4);
            *(f32x4*)(sXm + row * 1024 + ((uint32_t)(seg * 128 + q * 16) ^ ((row & 7u) << 4))) = v;
        }
    }
    // A fragments resident in regs (u_aug rows are block-exclusive; one HBM stream)
    s16x8 Afr[2][10];
#pragma unroll
    for (int fm = 0; fm < 2; ++fm)
#pragma unroll
        for (int ki = 0; ki < 10; ++ki)
            Afr[fm][ki] = *(const s16x8*)(actb + (size_t)(r0 + wm * 32 + fm * 16 + lr) * 640 + (ki * 32 + lk * 8) * 2);

    // einsum persistent state: thread -> (row er, slot); slots 0..2 = y1 d, 3..7 = y2 d
    const int er = tid >> 3, slot = tid & 7;
    const int region = (slot < 3) ? 1 : 2;
    const int d = (slot < 3) ? slot : slot - 3;
    float y[32];
#pragma unroll
    for (int o = 0; o < 32; ++o) y[o] = 0.f;
    const float norm = 0.17677669529663687f;

    f32x4 acc[2][4];
#define KB_CHUNK(BUF, KC) do { \
    _Pragma("unroll") for (int ks = 0; ks < 2; ++ks) \
    _Pragma("unroll") for (int fm = 0; fm < 2; ++fm) \
    _Pragma("unroll") for (int fn = 0; fn < 4; ++fn) \
        acc[fm][fn] = mfma16(Afr[fm][(KC) * 2 + ks], BUF[fn * 2 + ks], acc[fm][fn]); \
    issue(BUF); } while (0)

    for (int nt = 0; nt < 9; ++nt) {
        const int n0 = nt * 256;
#pragma unroll
        for (int fm = 0; fm < 2; ++fm)
#pragma unroll
            for (int fn = 0; fn < 4; ++fn) acc[fm][fn] = f32x4{0.f, 0.f, 0.f, 0.f};
        if (!(nt & 1)) { KB_CHUNK(B0, 0); KB_CHUNK(B1, 1); KB_CHUNK(B0, 2); KB_CHUNK(B1, 3); KB_CHUNK(B0, 4); }
        else           { KB_CHUNK(B1, 0); KB_CHUNK(B0, 1); KB_CHUNK(B1, 2); KB_CHUNK(B0, 3); KB_CHUNK(B1, 4); }
        asm volatile("s_nop 7\n\ts_nop 7");
        // epilogue: scalar cols -> out directly, w cols -> sW (+c2), pad cols dropped
#pragma unroll
        for (int fm = 0; fm < 2; ++fm)
#pragma unroll
            for (int fn = 0; fn < 4; ++fn) {
                int c = n0 + wn * 64 + fn * 16 + lr;
                float cc2 = c2[c];
#pragma unroll
                for (int ri = 0; ri < 4; ++ri) {
                    int rl = wm * 32 + fm * 16 + lk * 4 + ri;
                    float v = acc[fm][fn][ri] + cc2;
                    if (c < 128) out[(size_t)(r0 + rl) * OUTD + c] = v;
                    else if (c < NBIG) {
                        int cl = wn * 64 + fn * 16 + lr;
                        *(short*)(sWm + rl * 512 + ((uint32_t)(cl * 2) ^ ((rl & 7u) << 4))) = f2bs(v);
                    }
                }
            }
        __syncthreads();
        // fused einsum on this tile's w columns (x from sX, y in VGPRs with static indices)
        for (int islot = 0; islot < 8; ++islot) {
            int cb = n0 + islot * 32;
            if (cb < 128 || cb >= NBIG) continue;
            int treg = (cb < 1152) ? 1 : 2;
            if (treg != region) continue;
            int i = (cb - ((treg == 1) ? 128 : 1152)) >> 5;
            int xcol = ((treg == 1) ? 0 : 96) + i * ((treg == 1) ? 3 : 5) + d;
            float xv = *(const float*)(sXm + er * 1024 + ((uint32_t)(xcol * 4) ^ ((er & 7u) << 4)));
#pragma unroll
            for (int og = 0; og < 4; ++og) {
                uint32_t clb = (uint32_t)(islot * 64 + og * 16);
                s16x8 wv = *(const s16x8*)(sWm + er * 512 + (clb ^ ((er & 7u) << 4)));
#pragma unroll
                for (int j = 0; j < 8; ++j) y[og * 8 + j] += bs2f(wv[j]) * xv;
            }
        }
        __syncthreads();
    }
#undef KB_CHUNK
    // final equivariant writes
    float* orow = out + (size_t)(r0 + er) * OUTD;
    if (region == 1) {
#pragma unroll
        for (int o = 0; o < 32; ++o) orow[128 + o * 3 + d] = y[o] * norm;
    } else {
#pragma unroll
        for (int o = 0; o < 32; ++o) orow[224 + o * 5 + d] = y[o] * norm;
    }
}

extern "C" void kernel_launch(void* const* d_in, const int* in_sizes, int n_in,
                              void* d_out, int out_size, void* d_ws, size_t ws_size,
                              hipStream_t stream) {
    (void)in_sizes; (void)n_in; (void)out_size; (void)ws_size;
    const float* feat = (const float*)d_in[0];
    const float* cond = (const float*)d_in[1];
    const float* f1w  = (const float*)d_in[2];
    const float* f1b  = (const float*)d_in[3];
    const float* fc1  = (const float*)d_in[4];
    const float* f2w  = (const float*)d_in[5];
    const float* f2b  = (const float*)d_in[6];
    const float* invw = (const float*)d_in[7];
    const float* wemb = (const float*)d_in[8];
    char* ws = (char*)d_ws;
    float* out = (float*)d_out;

    k0a<<<128, 256, 0, stream>>>(f1w, f2w, ws);
    k0b<<<16, 256, 0, stream>>>(f1w, f1b, fc1, ws);
    k0c<<<137, 256, 0, stream>>>(f2w, f2b, invw, wemb, ws);
    af<<<1024, 512, 0, stream>>>(feat, cond, f1b, f2b, ws);
    kb<<<1024, 512, 0, stream>>>(feat, ws, out);
}